// Round 3
// baseline (571.264 us; speedup 1.0000x reference)
//
#include <hip/hip_runtime.h>
#include <hip/hip_bf16.h>
#include <stdint.h>

typedef __attribute__((ext_vector_type(8))) short short8;
typedef __attribute__((ext_vector_type(4))) float float4v;

__device__ __forceinline__ float bf2f(uint16_t u) {
    union { uint32_t i; float f; } v; v.i = ((uint32_t)u) << 16; return v.f;
}
__device__ __forceinline__ uint16_t f2bf(float f) {  // round-to-nearest-even
    union { float f; uint32_t i; } v; v.f = f;
    uint32_t x = v.i;
    uint32_t r = (x + 0x7fffu + ((x >> 16) & 1u)) >> 16;
    return (uint16_t)r;
}
// NaN-PROPAGATING relu: exact for normal x; NaN stays NaN (diagnostic).
__device__ __forceinline__ float relu_nanprop(float x) {
    return 0.5f * (x + fabsf(x));
}

// ---------------------------------------------------------------------------
// Kernel 1 (fp32 in): A1T[n][f] = sum_d W1[f][d]*Wm1[d][n]  (bf16 out, [64][1024])
//                     A2T likewise with Wm1 rows 128..255.
//                     tbias[n] = b1@Wm1_top + b2@Wm1_bot + bm1  (fp32)
// ---------------------------------------------------------------------------
__global__ __launch_bounds__(256) void precompute_kernel(
    const float* __restrict__ W1, const float* __restrict__ W2,
    const float* __restrict__ Wm1,
    const float* __restrict__ b1, const float* __restrict__ b2,
    const float* __restrict__ bm1,
    uint16_t* __restrict__ A1T, uint16_t* __restrict__ A2T,
    float* __restrict__ tbias)
{
    int b = blockIdx.x, t = threadIdx.x;
    if (b < 512) {
        int g   = b * 256 + t;         // 0 .. 131071
        int mat = g >> 16;             // 0: gene, 1: cell
        int rem = g & 65535;
        int n   = rem >> 10;           // 0..63
        int f   = rem & 1023;          // 0..1023
        const float* W  = mat ? W2 : W1;
        const float* wm = Wm1 + mat * 128 * 64;
        const float4* Wrow = (const float4*)(W + (size_t)f * 128);
        float acc = 0.f;
        #pragma unroll
        for (int c = 0; c < 32; ++c) {
            float4 w = Wrow[c];
            acc += w.x * wm[(c * 4 + 0) * 64 + n];
            acc += w.y * wm[(c * 4 + 1) * 64 + n];
            acc += w.z * wm[(c * 4 + 2) * 64 + n];
            acc += w.w * wm[(c * 4 + 3) * 64 + n];
        }
        (mat ? A2T : A1T)[(size_t)n * 1024 + f] = f2bf(acc);
    } else if (t < 64) {
        float acc = bm1[t];
        for (int d = 0; d < 128; ++d) acc += b1[d] * Wm1[d * 64 + t];
        for (int d = 0; d < 128; ++d) acc += b2[d] * Wm1[(128 + d) * 64 + t];
        tbias[t] = acc;
    }
}

// ---------------------------------------------------------------------------
// Kernel 2: G(bf16 [M][64]) = X(fp32 [M][1024]) @ B, B stored transposed
// (BT = A?T bf16 [64][1024]).  BM=128, BN=64, BK=64, 256 thr (4 waves),
// mfma_f32_16x16x32_bf16.  A tile: fp32 global -> reg -> bf16 pack ->
// ds_write b128, XOR chunk swizzle (chunk=8 bf16=16B; phys chunk pc of row r
// holds logical chunk pc^(r&7)) so stores & fragment reads stay b128, <=2-way
// banked.  B fragments per-lane from global (128 KB, L2-hot).
// ---------------------------------------------------------------------------
__global__ __launch_bounds__(256) void gemm64_kernel(
    const float* __restrict__ X1, const float* __restrict__ X2,
    const uint16_t* __restrict__ A1T, const uint16_t* __restrict__ A2T,
    uint16_t* __restrict__ G1, uint16_t* __restrict__ G2, int M1, int M2)
{
    const int which = blockIdx.y;
    const float* __restrict__ X     = which ? X2  : X1;
    const uint16_t* __restrict__ BT = which ? A2T : A1T;
    uint16_t* __restrict__ G        = which ? G2  : G1;
    const int M = which ? M2 : M1;

    const int blockRow = blockIdx.x * 128;
    if (blockRow >= M) return;

    __shared__ uint16_t As[128 * 64];   // 16 KB

    const int t    = threadIdx.x;
    const int wid  = t >> 6;
    const int lane = t & 63;
    const int m    = lane & 15;
    const int q    = lane >> 4;

    float4v acc[2][4];
    #pragma unroll
    for (int r = 0; r < 2; ++r)
        #pragma unroll
        for (int nt = 0; nt < 4; ++nt)
            acc[r][nt] = (float4v){0.f, 0.f, 0.f, 0.f};

    for (int kk = 0; kk < 16; ++kk) {
        // ---- load A tile (fp32) into registers, 8 floats per chunk ----
        float4 av0[4], av1[4];
        int    dstc[4];
        #pragma unroll
        for (int it = 0; it < 4; ++it) {
            int c   = it * 256 + t;        // chunk id 0..1023
            int row = c >> 3, pc = c & 7;
            int lc  = pc ^ (row & 7);      // logical chunk stored at pc
            int grow = blockRow + row; if (grow >= M) grow = M - 1;
            const float4* src = (const float4*)(X + (size_t)grow * 1024 + kk * 64 + lc * 8);
            av0[it] = src[0];
            av1[it] = src[1];
            dstc[it] = c * 8;
        }
        __syncthreads();                   // previous iter's readers done
        #pragma unroll
        for (int it = 0; it < 4; ++it) {
            uint4 pk;
            pk.x = (uint32_t)f2bf(av0[it].x) | ((uint32_t)f2bf(av0[it].y) << 16);
            pk.y = (uint32_t)f2bf(av0[it].z) | ((uint32_t)f2bf(av0[it].w) << 16);
            pk.z = (uint32_t)f2bf(av1[it].x) | ((uint32_t)f2bf(av1[it].y) << 16);
            pk.w = (uint32_t)f2bf(av1[it].z) | ((uint32_t)f2bf(av1[it].w) << 16);
            *(uint4*)(As + dstc[it]) = pk;
        }
        __syncthreads();                   // A tile visible

        #pragma unroll
        for (int s = 0; s < 2; ++s) {
            short8 af[2], bfr[4];
            #pragma unroll
            for (int r = 0; r < 2; ++r) {
                int row = wid * 32 + r * 16 + m;
                int pc  = (s * 4 + q) ^ (row & 7);
                af[r] = *(const short8*)(As + row * 64 + pc * 8);
            }
            #pragma unroll
            for (int nt = 0; nt < 4; ++nt) {
                int n = nt * 16 + m;
                // B[k = s*32+q*8+j][n] == BT[n][kk*64 + (s*4+q)*8 + j]
                bfr[nt] = *(const short8*)(BT + (size_t)n * 1024 + kk * 64 + (s * 4 + q) * 8);
            }
            #pragma unroll
            for (int r = 0; r < 2; ++r)
                #pragma unroll
                for (int nt = 0; nt < 4; ++nt)
                    acc[r][nt] = __builtin_amdgcn_mfma_f32_16x16x32_bf16(
                        af[r], bfr[nt], acc[r][nt], 0, 0, 0);
        }
    }

    // epilogue: C/D layout col = lane&15, row = q*4 + reg   [m89/m91 verified]
    #pragma unroll
    for (int r = 0; r < 2; ++r) {
        #pragma unroll
        for (int reg = 0; reg < 4; ++reg) {
            int grow = blockRow + wid * 32 + r * 16 + q * 4 + reg;
            if (grow < M) {
                #pragma unroll
                for (int nt = 0; nt < 4; ++nt)
                    G[(size_t)grow * 64 + nt * 16 + m] = f2bf(acc[r][nt][reg]);
            }
        }
    }
}

// ---------------------------------------------------------------------------
// Kernel 3: per-edge MLP.  t = relu(g1[src]+g2[dst]+tbias) ; u = t@Wm2+bm2 ;
//           pred = relu(u)@Wm3 + bm3.  One thread per edge, fp32 out.
// ---------------------------------------------------------------------------
__global__ __launch_bounds__(256) void edge_mlp_kernel(
    const uint16_t* __restrict__ g1, const uint16_t* __restrict__ g2,
    const float* __restrict__ tbias, const int* __restrict__ eidx,
    const float* __restrict__ Wm2, const float* __restrict__ bm2,
    const float* __restrict__ Wm3, const float* __restrict__ bm3,
    float* __restrict__ out, int E)
{
    int e = blockIdx.x * 256 + threadIdx.x;
    if (e >= E) e = E - 1;                 // clamp: uniform control flow
    int src = eidx[e];
    int dst = eidx[E + e];
    const uint4* r1 = (const uint4*)(g1 + (size_t)src * 64);
    const uint4* r2 = (const uint4*)(g2 + (size_t)dst * 64);

    float u[32];
    #pragma unroll
    for (int j = 0; j < 32; ++j) u[j] = bm2[j];

    #pragma unroll
    for (int c = 0; c < 8; ++c) {
        uint4 a = r1[c], b = r2[c];
        uint32_t aw[4] = { a.x, a.y, a.z, a.w };
        uint32_t bw[4] = { b.x, b.y, b.z, b.w };
        float tv[8];
        #pragma unroll
        for (int h = 0; h < 4; ++h) {
            float alo, ahi, blo, bhi;
            { union { uint32_t i; float f; } v; v.i = aw[h] << 16;        alo = v.f; }
            { union { uint32_t i; float f; } v; v.i = aw[h] & 0xffff0000u; ahi = v.f; }
            { union { uint32_t i; float f; } v; v.i = bw[h] << 16;        blo = v.f; }
            { union { uint32_t i; float f; } v; v.i = bw[h] & 0xffff0000u; bhi = v.f; }
            tv[2 * h]     = relu_nanprop(alo + blo + tbias[c * 8 + 2 * h]);
            tv[2 * h + 1] = relu_nanprop(ahi + bhi + tbias[c * 8 + 2 * h + 1]);
        }
        #pragma unroll
        for (int i = 0; i < 8; ++i) {
            const float* wrow = Wm2 + (c * 8 + i) * 32;
            #pragma unroll
            for (int j = 0; j < 32; ++j)
                u[j] = fmaf(tv[i], wrow[j], u[j]);
        }
    }

    float p = bm3[0];
    #pragma unroll
    for (int j = 0; j < 32; ++j)
        p += relu_nanprop(u[j]) * Wm3[j];
    out[e] = p;
}

// ---------------------------------------------------------------------------
extern "C" void kernel_launch(void* const* d_in, const int* in_sizes, int n_in,
                              void* d_out, int out_size, void* d_ws, size_t ws_size,
                              hipStream_t stream) {
    const float* x_gene = (const float*)d_in[0];
    const float* x_cell = (const float*)d_in[1];
    const int*   eidx   = (const int*)d_in[2];
    const float* W1  = (const float*)d_in[3];
    const float* b1  = (const float*)d_in[4];
    const float* W2  = (const float*)d_in[5];
    const float* b2  = (const float*)d_in[6];
    const float* Wm1 = (const float*)d_in[7];
    const float* bm1 = (const float*)d_in[8];
    const float* Wm2 = (const float*)d_in[9];
    const float* bm2 = (const float*)d_in[10];
    const float* Wm3 = (const float*)d_in[11];
    const float* bm3 = (const float*)d_in[12];

    const int M1 = in_sizes[0] / 1024;
    const int M2 = in_sizes[1] / 1024;
    const int E  = in_sizes[2] / 2;

    uint8_t* ws = (uint8_t*)d_ws;
    uint16_t* A1T   = (uint16_t*)(ws + 0);          // 131072 B
    uint16_t* A2T   = (uint16_t*)(ws + 131072);     // 131072 B
    float*    tbias = (float*)(ws + 262144);        //   256 B
    uint16_t* G1    = (uint16_t*)(ws + 524288);
    size_t g1_bytes = ((size_t)M1 * 64 * 2 + 127) & ~(size_t)127;
    uint16_t* G2    = (uint16_t*)(ws + 524288 + g1_bytes);

    precompute_kernel<<<513, 256, 0, stream>>>(
        W1, W2, Wm1, b1, b2, bm1, A1T, A2T, tbias);

    int Mmax = M1 > M2 ? M1 : M2;
    dim3 ggrid((Mmax + 127) / 128, 2);
    gemm64_kernel<<<ggrid, 256, 0, stream>>>(x_gene, x_cell, A1T, A2T, G1, G2, M1, M2);

    edge_mlp_kernel<<<(E + 255) / 256, 256, 0, stream>>>(
        G1, G2, tbias, eidx, Wm2, bm2, Wm3, bm3, (float*)d_out, E);
}